// Round 2
// baseline (183.100 us; speedup 1.0000x reference)
//
#include <hip/hip_runtime.h>
#include <math.h>

#define DIM 128

// ws layout: float sq[N]; float acc;

__global__ void __launch_bounds__(256)
sq_kernel(const float* __restrict__ x, float* __restrict__ sq,
          float* __restrict__ acc, int n_rows) {
    if (blockIdx.x == 0 && threadIdx.x == 0) *acc = 0.0f;
    int wave = (blockIdx.x * blockDim.x + threadIdx.x) >> 6;
    int lane = threadIdx.x & 63;
    if (wave >= n_rows) return;
    const float2* row = (const float2*)(x + (size_t)wave * DIM);
    float2 v = row[lane];                 // 64 lanes x float2 = 128 floats
    float s = v.x * v.x + v.y * v.y;
#pragma unroll
    for (int off = 32; off; off >>= 1) s += __shfl_xor(s, off, 64);
    if (lane == 0) sq[wave] = s;
}

__device__ __forceinline__ float softplus_stable(float z) {
    // log1p(exp(z)) = max(z,0) + log1p(exp(-|z|)) — finite for all z,
    // matches the harness's float64 numpy reference (which never overflows).
    return fmaxf(z, 0.0f) + log1pf(expf(-fabsf(z)));
}

__global__ void __launch_bounds__(256)
trip_kernel(const float* __restrict__ x, const int* __restrict__ trip,
            const float* __restrict__ sq, float* __restrict__ acc, int T) {
    int gwave  = (blockIdx.x * blockDim.x + threadIdx.x) >> 6;
    int lane   = threadIdx.x & 63;
    int half   = lane >> 5;               // which triplet of this wave's pair
    int sub    = lane & 31;               // lane within the half-wave
    int nwaves = (gridDim.x * blockDim.x) >> 6;

    float local = 0.0f;
    // T is even (200000): both halves of a pair are always in-bounds together.
    for (int pair = gwave; 2 * pair < T; pair += nwaves) {
        int n = 2 * pair + half;
        int i = trip[3 * n];
        int j = trip[3 * n + 1];
        int k = trip[3 * n + 2];
        const float4* xi = (const float4*)(x + (size_t)i * DIM);
        const float4* xj = (const float4*)(x + (size_t)j * DIM);
        const float4* xk = (const float4*)(x + (size_t)k * DIM);
        float4 a4 = xi[sub];              // 32 lanes x float4 = full row, coalesced
        float4 b4 = xj[sub];
        float4 c4 = xk[sub];
        float a = a4.x * b4.x + a4.y * b4.y + a4.z * b4.z + a4.w * b4.w;
        float b = a4.x * c4.x + a4.y * c4.y + a4.z * c4.z + a4.w * c4.w;
#pragma unroll
        for (int off = 16; off; off >>= 1) {   // butterfly within each 32-lane half
            a += __shfl_xor(a, off, 64);
            b += __shfl_xor(b, off, 64);
        }
        if (sub == 0) {
            float d1 = fmaxf(sq[i] + sq[j] - 2.0f * a, 0.0f);
            float d2 = fmaxf(sq[i] + sq[k] - 2.0f * b, 0.0f);
            local += softplus_stable(d1 - d2);
        }
    }
    // lanes 0 and 32 hold the two partial sums; fold and one atomic per wave
    local += __shfl_xor(local, 32, 64);
    if (lane == 0) atomicAdd(acc, local);
}

__global__ void finalize_kernel(const float* __restrict__ acc,
                                float* __restrict__ out, int T) {
    out[0] = acc[0] / (float)T;
}

extern "C" void kernel_launch(void* const* d_in, const int* in_sizes, int n_in,
                              void* d_out, int out_size, void* d_ws, size_t ws_size,
                              hipStream_t stream) {
    const float* x    = (const float*)d_in[0];
    const int*   trip = (const int*)d_in[1];
    float*       out  = (float*)d_out;

    int n_rows = in_sizes[0] / DIM;       // 8192
    int T      = in_sizes[1] / 3;         // 200000

    float* sq  = (float*)d_ws;
    float* acc = sq + n_rows;

    // 1) row norms + zero accumulator (ws is poisoned before every call)
    int sq_blocks = (n_rows + 3) / 4;     // 4 waves (rows) per 256-thread block
    sq_kernel<<<sq_blocks, 256, 0, stream>>>(x, sq, acc, n_rows);

    // 2) main gather: 2048 blocks = 8192 waves = 16384 triplets in flight
    trip_kernel<<<2048, 256, 0, stream>>>(x, trip, sq, acc, T);

    // 3) mean
    finalize_kernel<<<1, 1, 0, stream>>>(acc, out, T);
}

// Round 3
// 93.537 us; speedup vs baseline: 1.9575x; 1.9575x over previous
//
#include <hip/hip_runtime.h>
#include <math.h>

#define DIM 128
#define TRIP_BLOCKS 4096

// ws layout: float sq[8192]; float partial[TRIP_BLOCKS];

__global__ void __launch_bounds__(256)
sq_kernel(const float* __restrict__ x, float* __restrict__ sq, int n_rows) {
    int wave = (blockIdx.x * blockDim.x + threadIdx.x) >> 6;
    int lane = threadIdx.x & 63;
    if (wave >= n_rows) return;
    const float2* row = (const float2*)(x + (size_t)wave * DIM);
    float2 v = row[lane];                 // 64 lanes x float2 = 128 floats
    float s = v.x * v.x + v.y * v.y;
#pragma unroll
    for (int off = 32; off; off >>= 1) s += __shfl_xor(s, off, 64);
    if (lane == 0) sq[wave] = s;
}

__device__ __forceinline__ float softplus_stable(float z) {
    // log1p(exp(z)) = max(z,0) + log1p(exp(-|z|)) — finite for all z.
    return fmaxf(z, 0.0f) + log1pf(expf(-fabsf(z)));
}

__global__ void __launch_bounds__(256)
trip_kernel(const float* __restrict__ x, const int* __restrict__ trip,
            const float* __restrict__ sq, float* __restrict__ partial, int T) {
    int gwave  = (blockIdx.x * blockDim.x + threadIdx.x) >> 6;
    int lane   = threadIdx.x & 63;
    int half   = lane >> 5;               // which triplet of this wave's pair
    int sub    = lane & 31;               // lane within the half-wave
    int nwaves = (gridDim.x * blockDim.x) >> 6;

    float local = 0.0f;
    // T is even (200000): both halves of a pair are always in-bounds together.
    for (int pair = gwave; 2 * pair < T; pair += nwaves) {
        int n = 2 * pair + half;
        int i = trip[3 * n];
        int j = trip[3 * n + 1];
        int k = trip[3 * n + 2];
        const float4* xi = (const float4*)(x + (size_t)i * DIM);
        const float4* xj = (const float4*)(x + (size_t)j * DIM);
        const float4* xk = (const float4*)(x + (size_t)k * DIM);
        float4 a4 = xi[sub];              // 32 lanes x float4 = full row, coalesced
        float4 b4 = xj[sub];
        float4 c4 = xk[sub];
        float a = a4.x * b4.x + a4.y * b4.y + a4.z * b4.z + a4.w * b4.w;
        float b = a4.x * c4.x + a4.y * c4.y + a4.z * c4.z + a4.w * c4.w;
#pragma unroll
        for (int off = 16; off; off >>= 1) {   // butterfly within each 32-lane half
            a += __shfl_xor(a, off, 64);
            b += __shfl_xor(b, off, 64);
        }
        if (sub == 0) {
            float d1 = fmaxf(sq[i] + sq[j] - 2.0f * a, 0.0f);
            float d2 = fmaxf(sq[i] + sq[k] - 2.0f * b, 0.0f);
            local += softplus_stable(d1 - d2);
        }
    }
    // lanes 0 and 32 hold the two partial sums; fold so lane 0 has wave total
    local += __shfl_xor(local, 32, 64);

    // block reduction through LDS — NO global atomics (they serialized R1)
    __shared__ float wsum[4];
    int wid = threadIdx.x >> 6;
    if (lane == 0) wsum[wid] = local;
    __syncthreads();
    if (threadIdx.x == 0)
        partial[blockIdx.x] = wsum[0] + wsum[1] + wsum[2] + wsum[3];
}

__global__ void __launch_bounds__(256)
finalize_kernel(const float* __restrict__ partial, int nparts,
                float* __restrict__ out, int T) {
    float s = 0.0f;
    for (int idx = threadIdx.x; idx < nparts; idx += 256)
        s += partial[idx];
#pragma unroll
    for (int off = 32; off; off >>= 1) s += __shfl_xor(s, off, 64);
    __shared__ float wsum[4];
    int wid = threadIdx.x >> 6;
    if ((threadIdx.x & 63) == 0) wsum[wid] = s;
    __syncthreads();
    if (threadIdx.x == 0)
        out[0] = (wsum[0] + wsum[1] + wsum[2] + wsum[3]) / (float)T;
}

extern "C" void kernel_launch(void* const* d_in, const int* in_sizes, int n_in,
                              void* d_out, int out_size, void* d_ws, size_t ws_size,
                              hipStream_t stream) {
    const float* x    = (const float*)d_in[0];
    const int*   trip = (const int*)d_in[1];
    float*       out  = (float*)d_out;

    int n_rows = in_sizes[0] / DIM;       // 8192
    int T      = in_sizes[1] / 3;         // 200000

    float* sq      = (float*)d_ws;
    float* partial = sq + n_rows;

    // 1) row norms
    int sq_blocks = (n_rows + 3) / 4;     // 4 waves (rows) per 256-thread block
    sq_kernel<<<sq_blocks, 256, 0, stream>>>(x, sq, n_rows);

    // 2) main gather: 4096 blocks = 16384 waves, ~6 pair-iterations each
    trip_kernel<<<TRIP_BLOCKS, 256, 0, stream>>>(x, trip, sq, partial, T);

    // 3) reduce partials + mean
    finalize_kernel<<<1, 256, 0, stream>>>(partial, TRIP_BLOCKS, out, T);
}

// Round 4
// 78.469 us; speedup vs baseline: 2.3334x; 1.1920x over previous
//
#include <hip/hip_runtime.h>
#include <math.h>

#define DIM 128
#define TRIP_BLOCKS 2048   // 8 blocks/CU x 256 CUs: fully resident, no tail

// ws layout: float partial[TRIP_BLOCKS];

// DPP row_shr:N add — VALU-pipe cross-lane, no DS traffic.
// bound_ctrl=true: out-of-row lanes read 0.
template<int CTRL>
__device__ __forceinline__ float dpp_shr_add(float v) {
    int m = __builtin_amdgcn_update_dpp(0, __float_as_int(v), CTRL, 0xf, 0xf, true);
    return v + __int_as_float(m);
}

// Sum across a 16-lane DPP row; lane 15 of each row ends with the row sum.
__device__ __forceinline__ float row16_sum(float v) {
    v = dpp_shr_add<0x111>(v);   // row_shr:1
    v = dpp_shr_add<0x112>(v);   // row_shr:2
    v = dpp_shr_add<0x114>(v);   // row_shr:4
    v = dpp_shr_add<0x118>(v);   // row_shr:8
    return v;
}

__device__ __forceinline__ float softplus_stable(float z) {
    // log1p(exp(z)) = max(z,0) + log1p(exp(-|z|)) — finite for all z,
    // matches the harness's float64 numpy reference (never overflows).
    return fmaxf(z, 0.0f) + log1pf(expf(-fabsf(z)));
}

__global__ void __launch_bounds__(256)
trip_kernel(const float* __restrict__ x, const int* __restrict__ trip,
            float* __restrict__ partial, int T) {
    int gwave  = (blockIdx.x * blockDim.x + threadIdx.x) >> 6;
    int lane   = threadIdx.x & 63;
    int g      = lane >> 4;               // 16-lane group (DPP row) = one triplet
    int sub    = lane & 15;
    int ngroups = (gridDim.x * blockDim.x) >> 4;

    float local = 0.0f;
    for (int n = gwave * 4 + g; n < T; n += ngroups) {
        int i = trip[3 * n];
        int j = trip[3 * n + 1];
        int k = trip[3 * n + 2];
        const float4* xi = (const float4*)(x + ((size_t)i << 7));
        const float4* xj = (const float4*)(x + ((size_t)j << 7));
        const float4* xk = (const float4*)(x + ((size_t)k << 7));
        // 16 lanes x (2 float4) = 128 floats per row; two 256B coalesced segments
        float4 a0 = xi[sub], a1 = xi[sub + 16];
        float4 b0 = xj[sub], b1 = xj[sub + 16];
        float4 c0 = xk[sub], c1 = xk[sub + 16];

        // d_ij = sum (xi - xj)^2  — algebraically identical to sq_i+sq_j-2ab,
        // exactly >= 0 so no clamp needed, and no sq[] table at all.
        float t, d1 = 0.0f, d2 = 0.0f;
        t = a0.x - b0.x; d1 = fmaf(t, t, d1);
        t = a0.y - b0.y; d1 = fmaf(t, t, d1);
        t = a0.z - b0.z; d1 = fmaf(t, t, d1);
        t = a0.w - b0.w; d1 = fmaf(t, t, d1);
        t = a1.x - b1.x; d1 = fmaf(t, t, d1);
        t = a1.y - b1.y; d1 = fmaf(t, t, d1);
        t = a1.z - b1.z; d1 = fmaf(t, t, d1);
        t = a1.w - b1.w; d1 = fmaf(t, t, d1);
        t = a0.x - c0.x; d2 = fmaf(t, t, d2);
        t = a0.y - c0.y; d2 = fmaf(t, t, d2);
        t = a0.z - c0.z; d2 = fmaf(t, t, d2);
        t = a0.w - c0.w; d2 = fmaf(t, t, d2);
        t = a1.x - c1.x; d2 = fmaf(t, t, d2);
        t = a1.y - c1.y; d2 = fmaf(t, t, d2);
        t = a1.z - c1.z; d2 = fmaf(t, t, d2);
        t = a1.w - c1.w; d2 = fmaf(t, t, d2);

        d1 = row16_sum(d1);               // 4 DPP adds, VALU pipe only
        d2 = row16_sum(d2);
        if (sub == 15)
            local += softplus_stable(d1 - d2);
    }

    // lanes 15/31/47/63 hold per-group sums; two DS shuffles per wave total
    local += __shfl_xor(local, 16, 64);
    local += __shfl_xor(local, 32, 64);   // lanes {15,31,47,63} now = wave total

    __shared__ float wsum[4];
    int wid = threadIdx.x >> 6;
    if (lane == 15) wsum[wid] = local;
    __syncthreads();
    if (threadIdx.x == 0)
        partial[blockIdx.x] = wsum[0] + wsum[1] + wsum[2] + wsum[3];
}

__global__ void __launch_bounds__(256)
finalize_kernel(const float* __restrict__ partial, int nparts,
                float* __restrict__ out, int T) {
    float s = 0.0f;
    for (int idx = threadIdx.x; idx < nparts; idx += 256)
        s += partial[idx];
#pragma unroll
    for (int off = 32; off; off >>= 1) s += __shfl_xor(s, off, 64);
    __shared__ float wsum[4];
    int wid = threadIdx.x >> 6;
    if ((threadIdx.x & 63) == 0) wsum[wid] = s;
    __syncthreads();
    if (threadIdx.x == 0)
        out[0] = (wsum[0] + wsum[1] + wsum[2] + wsum[3]) / (float)T;
}

extern "C" void kernel_launch(void* const* d_in, const int* in_sizes, int n_in,
                              void* d_out, int out_size, void* d_ws, size_t ws_size,
                              hipStream_t stream) {
    const float* x    = (const float*)d_in[0];
    const int*   trip = (const int*)d_in[1];
    float*       out  = (float*)d_out;

    int T = in_sizes[1] / 3;              // 200000

    float* partial = (float*)d_ws;

    trip_kernel<<<TRIP_BLOCKS, 256, 0, stream>>>(x, trip, partial, T);
    finalize_kernel<<<1, 256, 0, stream>>>(partial, TRIP_BLOCKS, out, T);
}